// Round 21
// baseline (70.547 us; speedup 1.0000x reference)
//
#include <hip/hip_runtime.h>

namespace {

typedef _Float16 half8 __attribute__((ext_vector_type(8)));
typedef float f32x16 __attribute__((ext_vector_type(16)));

constexpr int Bb = 4, Nn = 8192, KNB = 6;
constexpr int KCAP = 64;                     // knn candidate slots per query (u32 keys)
constexpr int KNN_BLOCKS = Nn / 32;          // 256 (32 queries/block, 4 waves split tiles)
constexpr int CH_BLOCKS = 1024;              // 8 bd * 8 eighths * 16 qgroups
constexpr int TAIL_BLOCKS = 128;

struct KnnSmem {
    unsigned cand[32][KCAP];                 // 8 KB
    float Tbuf[128];
    int cnt[32];
    float part[32];
};

__device__ inline unsigned ordkey(float f) {
    unsigned b = __float_as_uint(f);
    return b ^ (unsigned)(((int)b >> 31) | 0x80000000);
}

__device__ inline half8 zero8() {
    half8 v;
    #pragma unroll
    for (int i = 0; i < 8; ++i) v[i] = (_Float16)0;
    return v;
}

// Consistent single-f16 scheme (kg0 slots only; kg1 lanes zero on B side):
//   acc = -p̂·q̂ + |p̂|²/2 ; d2 = |q̂|² + 2·acc = |q̂-p̂|² ± ~7e-6 (clamped >= 0)
__device__ inline half8 a_frag(float x, float y, float z) {
    _Float16 hx = (_Float16)x, hy = (_Float16)y, hz = (_Float16)z;
    const float xr = (float)hx, yr = (float)hy, zr = (float)hz;
    const float pp5 = 0.5f * (xr * xr + yr * yr + zr * zr);
    _Float16 ph = (_Float16)pp5, pl = (_Float16)(pp5 - (float)ph);
    half8 v;
    v[0] = -hx; v[1] = -hy; v[2] = -hz; v[3] = ph; v[4] = pl;
    v[5] = (_Float16)0; v[6] = (_Float16)0; v[7] = (_Float16)0;
    return v;
}
__device__ inline half8 b_frag(float x, float y, float z) {
    _Float16 hx = (_Float16)x, hy = (_Float16)y, hz = (_Float16)z;
    half8 v;
    v[0] = hx; v[1] = hy; v[2] = hz; v[3] = (_Float16)1; v[4] = (_Float16)1;
    v[5] = (_Float16)0; v[6] = (_Float16)0; v[7] = (_Float16)0;
    return v;
}

// ---- init: mins -> +inf, acc -> 0, precompute ALL point fragments ----
__global__ void init_ws_kernel(unsigned* __restrict__ minArr, float* __restrict__ acc,
                               half8* __restrict__ tmplFrag, half8* __restrict__ pFrag,
                               half8* __restrict__ tFrag, const float* __restrict__ tmpl,
                               const float* __restrict__ disp,
                               const float* __restrict__ targ) {
    const int i = blockIdx.x * blockDim.x + threadIdx.x;
    if (i < 2 * Bb * Nn) minArr[i] = 0x7f800000u;
    if (i < 8) acc[i] = 0.0f;
    if (i < Nn) {   // template[0] frags for knn
        tmplFrag[i] = a_frag(tmpl[i * 3 + 0], tmpl[i * 3 + 1], tmpl[i * 3 + 2]);
    }
    if (i < Bb * Nn) {   // per-(b,point) frags for chamfer; (b*Nn+p) == i
        const long e = (long)i * 3;
        tFrag[i] = a_frag(targ[e], targ[e + 1], targ[e + 2]);
        pFrag[i] = a_frag(tmpl[e] + disp[e], tmpl[e + 1] + disp[e + 1],
                          tmpl[e + 2] + disp[e + 2]);
    }
}

// ------- fat kernel: knn-mfma blocks [0,256) + barrier-free chamfer [256,1280) ----
__global__ __launch_bounds__(256, 6) void fat_kernel(
    const float* __restrict__ disp, const float* __restrict__ tmpl,
    const float* __restrict__ targ, unsigned* __restrict__ outMin,
    float* __restrict__ acc, const half8* __restrict__ tmplFrag,
    const half8* __restrict__ pFrag, const half8* __restrict__ tFrag) {
    __shared__ KnnSmem sm;
    const int tid = threadIdx.x;
    const f32x16 zc = {0.f, 0.f, 0.f, 0.f, 0.f, 0.f, 0.f, 0.f,
                       0.f, 0.f, 0.f, 0.f, 0.f, 0.f, 0.f, 0.f};

    if (blockIdx.x >= KNN_BLOCKS) {
        // ===== chamfer via MFMA, global precomputed frags, no LDS, no barriers =====
        const int cb = (int)blockIdx.x - KNN_BLOCKS;   // 0..1023
        const int qbase = (cb & 15) * 512;
        const int eighth = (cb >> 4) & 7;
        const int bd = cb >> 7;                        // 0..7
        const int dir = bd & 1, b = bd >> 1;
        const int lane = tid & 63, w = tid >> 6;
        const int l31 = lane & 31, kg = lane >> 5;

        float qq[4];
        half8 Bf[4];
        #pragma unroll
        for (int j = 0; j < 4; ++j) {
            const int q = qbase + w * 128 + j * 32 + l31;
            const long e = ((long)b * Nn + q) * 3;
            float x, y, z;
            if (dir == 0) {   // queries = pred
                x = tmpl[e] + disp[e]; y = tmpl[e+1] + disp[e+1]; z = tmpl[e+2] + disp[e+2];
            } else {          // queries = targ
                x = targ[e]; y = targ[e+1]; z = targ[e+2];
            }
            _Float16 hx = (_Float16)x, hy = (_Float16)y, hz = (_Float16)z;
            const float xr = (float)hx, yr = (float)hy, zr = (float)hz;
            qq[j] = xr * xr + yr * yr + zr * zr;
            Bf[j] = (kg == 0) ? b_frag(x, y, z) : zero8();
        }

        // points = the other set's frags, this (b, eighth)
        const half8* pf = ((dir == 0) ? tFrag : pFrag) + (long)b * Nn + eighth * 1024;

        float run[4] = {1e38f, 1e38f, 1e38f, 1e38f};

        #pragma unroll 1
        for (int g = 0; g < 8; ++g) {        // 8 groups x 4-deep batched loads
            half8 a[4];
            #pragma unroll
            for (int k = 0; k < 4; ++k)
                a[k] = pf[(g * 4 + k) * 32 + l31];
            #pragma unroll
            for (int k = 0; k < 4; ++k) {
                #pragma unroll
                for (int j = 0; j < 4; ++j) {
                    f32x16 c = __builtin_amdgcn_mfma_f32_32x32x16_f16(a[k], Bf[j], zc, 0, 0, 0);
                    #pragma unroll
                    for (int r = 0; r < 16; r += 2)
                        run[j] = fminf(run[j], fminf(c[r], c[r + 1]));  // -> v_min3_f32
                }
            }
        }

        #pragma unroll
        for (int j = 0; j < 4; ++j)
            run[j] = fminf(run[j], __shfl_xor(run[j], 32, 64));
        if (lane < 32) {
            const long base = ((long)dir * Bb + b) * Nn;
            #pragma unroll
            for (int j = 0; j < 4; ++j) {
                const int q = qbase + w * 128 + j * 32 + l31;
                const float d2 = fmaxf(fmaf(2.0f, run[j], qq[j]), 0.0f);
                atomicMin(&outMin[base + q], __float_as_uint(d2));
            }
        }
    } else {
        // ====== knn via MFMA, global frags, 8-deep load batching (r20 verbatim) ======
        const int kb = blockIdx.x;                     // 0..255
        const int lane = tid & 63, wid = tid >> 6;
        const int l31 = lane & 31, hi = lane >> 5;
        const int q = kb * 32 + l31;
        const float INFf = __uint_as_float(0x7f800000u);

        half8 Bf;
        {
            const float x = tmpl[q * 3 + 0], y = tmpl[q * 3 + 1], z = tmpl[q * 3 + 2];
            Bf = (hi == 0) ? b_frag(x, y, z) : zero8();
        }

        if (tid < 32) sm.cnt[tid] = 0;

        float cmn[16];
        #pragma unroll
        for (int r = 0; r < 16; ++r) cmn[r] = INFf;

        // ---- phase A: 8 batches of {8 loads in flight -> 8 MFMA+fmin} ----
        #pragma unroll 1
        for (int g = 0; g < 8; ++g) {
            half8 a[8];
            #pragma unroll
            for (int j = 0; j < 8; ++j)
                a[j] = tmplFrag[(wid * 64 + g * 8 + j) * 32 + l31];
            #pragma unroll
            for (int j = 0; j < 8; ++j) {
                f32x16 c = __builtin_amdgcn_mfma_f32_32x32x16_f16(a[j], Bf, zc, 0, 0, 0);
                #pragma unroll
                for (int r = 0; r < 16; ++r) cmn[r] = fminf(cmn[r], c[r]);
            }
        }

        // ---- per-wave T_w = 7th-smallest of its 32 chunk-mins ----
        float Tw = INFf;
        #pragma unroll
        for (int t = 0; t < 7; ++t) {
            float h = cmn[0];
            #pragma unroll
            for (int r = 1; r < 16; ++r) h = fminf(h, cmn[r]);
            h = fminf(h, __shfl_xor(h, 32, 64));
            Tw = h;
            #pragma unroll
            for (int r = 0; r < 16; ++r) cmn[r] = (cmn[r] == h) ? INFf : cmn[r];
        }
        if (hi == 0) sm.Tbuf[wid * 32 + l31] = Tw;
        __syncthreads();
        // T = min over the 4 waves: valid bound (argmin wave's quarter has >=7 pts <= T)
        const float T = fminf(fminf(sm.Tbuf[l31], sm.Tbuf[32 + l31]),
                              fminf(sm.Tbuf[64 + l31], sm.Tbuf[96 + l31]));

        // ---- phase B: rescan own tiles (batched); collect candidates (c <= T) ----
        #pragma unroll 1
        for (int g = 0; g < 8; ++g) {
            half8 a[8];
            #pragma unroll
            for (int j = 0; j < 8; ++j)
                a[j] = tmplFrag[(wid * 64 + g * 8 + j) * 32 + l31];
            #pragma unroll
            for (int j = 0; j < 8; ++j) {
                const int tt = wid * 64 + g * 8 + j;
                f32x16 c = __builtin_amdgcn_mfma_f32_32x32x16_f16(a[j], Bf, zc, 0, 0, 0);
                #pragma unroll
                for (int r = 0; r < 16; ++r) {
                    if (c[r] <= T) {
                        const int row = (r & 3) + 8 * (r >> 2) + 4 * hi;   // verified C/D map
                        const int p = tt * 32 + row;
                        const unsigned key = (ordkey(c[r]) & 0xFFFFE000u) | (unsigned)p;
                        const int pos = atomicAdd(&sm.cnt[l31], 1);
                        if (pos < KCAP) sm.cand[l31][pos] = key;
                    }
                }
            }
        }
        __syncthreads();

        // ---- exact top-7 (f16 metric, index tie-break) + smooth; 1 thread/query ----
        if (tid < 32) {
            const int qs = kb * 32 + tid;
            const int m = min(sm.cnt[tid], KCAP);
            unsigned l0 = ~0u, l1 = ~0u, l2 = ~0u, l3 = ~0u,
                     l4 = ~0u, l5 = ~0u, l6 = ~0u;
            for (int t = 0; t < m; ++t) {
                const unsigned key = sm.cand[tid][t];
                if (key < l6) {
                    l6 = key;
                    if (l6 < l5) { auto tt = l5; l5 = l6; l6 = tt; }
                    if (l5 < l4) { auto tt = l4; l4 = l5; l5 = tt; }
                    if (l4 < l3) { auto tt = l3; l3 = l4; l4 = tt; }
                    if (l3 < l2) { auto tt = l2; l2 = l3; l3 = tt; }
                    if (l2 < l1) { auto tt = l1; l1 = l2; l2 = tt; }
                    if (l1 < l0) { auto tt = l0; l0 = l1; l1 = tt; }
                }
            }
            // l0 = self (global-min); neighbors l1..l6
            int nb[6] = { (int)(l1 & 0x1FFFu), (int)(l2 & 0x1FFFu), (int)(l3 & 0x1FFFu),
                          (int)(l4 & 0x1FFFu), (int)(l5 & 0x1FFFu), (int)(l6 & 0x1FFFu) };
            float s = 0.0f;
            #pragma unroll
            for (int k = 0; k < 6; ++k) {
                const int j = nb[k];
                #pragma unroll
                for (int bb = 0; bb < Bb; ++bb) {
                    const float* dn = disp + ((long)bb * Nn + qs) * 3;
                    const float* dj = disp + ((long)bb * Nn + j) * 3;
                    const float ddx = dj[0] - dn[0];
                    const float ddy = dj[1] - dn[1];
                    const float ddz = dj[2] - dn[2];
                    s += ddx * ddx + ddy * ddy + ddz * ddz;
                }
            }
            sm.part[tid] = s;
        }
        __syncthreads();
        if (tid == 0) {
            float tot = 0.0f;
            #pragma unroll
            for (int i = 0; i < 32; ++i) tot += sm.part[i];
            atomicAdd(&acc[3], tot);
        }
    }
}

// ---- fused tail: reductions + last-block finalize ----
__global__ __launch_bounds__(256) void tail_reduce_kernel(
    const float* __restrict__ minArr, const float* __restrict__ pm,
    const float* __restrict__ tm, const float* __restrict__ dp,
    float* __restrict__ acc, float* __restrict__ out) {
    const int tid = threadIdx.x;
    const int stride = gridDim.x * blockDim.x;
    float sc = 0.0f, sm = 0.0f, sd = 0.0f;
    for (int i = blockIdx.x * blockDim.x + tid; i < 2 * Bb * Nn; i += stride) {
        sc += sqrtf(fmaxf(minArr[i], 1e-12f));
    }
    for (int i = blockIdx.x * blockDim.x + tid; i < Bb * Nn * 4; i += stride) {
        float d = pm[i] - tm[i];
        sm += d * d;
    }
    for (int i = blockIdx.x * blockDim.x + tid; i < Bb * Nn * 3; i += stride) {
        float v = dp[i];
        sd += v * v;
    }
    __shared__ float r0[256], r1[256], r2[256];
    r0[tid] = sc; r1[tid] = sm; r2[tid] = sd;
    __syncthreads();
    for (int w = 128; w > 0; w >>= 1) {
        if (tid < w) { r0[tid] += r0[tid + w]; r1[tid] += r1[tid + w]; r2[tid] += r2[tid + w]; }
        __syncthreads();
    }
    if (tid == 0) {
        atomicAdd(&acc[0], r0[0]);
        atomicAdd(&acc[1], r1[0]);
        atomicAdd(&acc[2], r2[0]);
        __threadfence();
        const unsigned done = atomicAdd((unsigned*)&acc[7], 1u);
        if (done == (unsigned)(gridDim.x - 1)) {
            const float c0 = atomicAdd(&acc[0], 0.0f);
            const float c1 = atomicAdd(&acc[1], 0.0f);
            const float c2 = atomicAdd(&acc[2], 0.0f);
            const float c3 = atomicAdd(&acc[3], 0.0f);
            const float cd  = c0 / (2.0f * Bb * Nn);
            const float mat = c1 / (float)(Bb * Nn * 4);
            const float dr  = c2 / (float)(Bb * Nn * 3);
            const float smo = c3 / (float)(Bb * Nn * KNB * 3);
            out[0] = 1.0f * cd + 0.1f * mat + 0.01f * dr + 0.005f * smo;
        }
    }
}

}  // namespace

extern "C" void kernel_launch(void* const* d_in, const int* in_sizes, int n_in,
                              void* d_out, int out_size, void* d_ws, size_t ws_size,
                              hipStream_t stream) {
    const float* pred_disp  = (const float*)d_in[0];
    const float* pred_mat   = (const float*)d_in[1];
    const float* target_pos = (const float*)d_in[2];
    const float* target_mat = (const float*)d_in[3];
    const float* tmpl       = (const float*)d_in[4];

    char* ws = (char*)d_ws;
    unsigned* minArr = (unsigned*)ws;                       // 256 KB
    float* acc = (float*)(ws + 262144);                     // 64 B
    half8* tmplFrag = (half8*)(ws + 262144 + 64);           // 128 KB
    half8* pFrag = (half8*)(ws + 262144 + 64 + 131072);     // 512 KB
    half8* tFrag = (half8*)(ws + 262144 + 64 + 131072 + 524288);  // 512 KB

    init_ws_kernel<<<(Bb * Nn) / 256 + 32, 256, 0, stream>>>(
        minArr, acc, tmplFrag, pFrag, tFrag, tmpl, pred_disp, target_pos);

    fat_kernel<<<KNN_BLOCKS + CH_BLOCKS, 256, 0, stream>>>(
        pred_disp, tmpl, target_pos, minArr, acc, tmplFrag, pFrag, tFrag);

    tail_reduce_kernel<<<TAIL_BLOCKS, 256, 0, stream>>>(
        (const float*)minArr, pred_mat, target_mat, pred_disp, acc, (float*)d_out);
}

// Round 22
// 65.901 us; speedup vs baseline: 1.0705x; 1.0705x over previous
//
#include <hip/hip_runtime.h>

namespace {

typedef _Float16 half8 __attribute__((ext_vector_type(8)));
typedef float f32x16 __attribute__((ext_vector_type(16)));

constexpr int Bb = 4, Nn = 8192, KNB = 6;
constexpr int KCAP = 64;                     // knn candidate slots per query (u32 keys)
constexpr int KNN_BLOCKS = 256;              // 32 queries/block, 8 waves split 256 tiles
constexpr int CH_BLOCKS = 512;               // 2 chamfer units per 512-thread block
constexpr int TAIL_BLOCKS = 128;

struct KnnSmem {
    unsigned cand[32][KCAP];                 // 8 KB
    float Tbuf[256];                         // 8 waves x 32 queries
    int cnt[32];
    float part[32];
};

__device__ inline unsigned ordkey(float f) {
    unsigned b = __float_as_uint(f);
    return b ^ (unsigned)(((int)b >> 31) | 0x80000000);
}

__device__ inline half8 zero8() {
    half8 v;
    #pragma unroll
    for (int i = 0; i < 8; ++i) v[i] = (_Float16)0;
    return v;
}

// Consistent single-f16 scheme (kg0 slots only; kg1 lanes zero on B side):
//   acc = -p̂·q̂ + |p̂|²/2 ; d2 = |q̂|² + 2·acc = |q̂-p̂|² ± ~7e-6 (clamped >= 0)
__device__ inline half8 a_frag(float x, float y, float z) {
    _Float16 hx = (_Float16)x, hy = (_Float16)y, hz = (_Float16)z;
    const float xr = (float)hx, yr = (float)hy, zr = (float)hz;
    const float pp5 = 0.5f * (xr * xr + yr * yr + zr * zr);
    _Float16 ph = (_Float16)pp5, pl = (_Float16)(pp5 - (float)ph);
    half8 v;
    v[0] = -hx; v[1] = -hy; v[2] = -hz; v[3] = ph; v[4] = pl;
    v[5] = (_Float16)0; v[6] = (_Float16)0; v[7] = (_Float16)0;
    return v;
}
__device__ inline half8 b_frag(float x, float y, float z) {
    _Float16 hx = (_Float16)x, hy = (_Float16)y, hz = (_Float16)z;
    half8 v;
    v[0] = hx; v[1] = hy; v[2] = hz; v[3] = (_Float16)1; v[4] = (_Float16)1;
    v[5] = (_Float16)0; v[6] = (_Float16)0; v[7] = (_Float16)0;
    return v;
}

// ---- init: mins -> +inf, acc -> 0, precompute ALL point fragments ----
__global__ void init_ws_kernel(unsigned* __restrict__ minArr, float* __restrict__ acc,
                               half8* __restrict__ tmplFrag, half8* __restrict__ pFrag,
                               half8* __restrict__ tFrag, const float* __restrict__ tmpl,
                               const float* __restrict__ disp,
                               const float* __restrict__ targ) {
    const int i = blockIdx.x * blockDim.x + threadIdx.x;
    if (i < 2 * Bb * Nn) minArr[i] = 0x7f800000u;
    if (i < 8) acc[i] = 0.0f;
    if (i < Nn) {   // template[0] frags for knn
        tmplFrag[i] = a_frag(tmpl[i * 3 + 0], tmpl[i * 3 + 1], tmpl[i * 3 + 2]);
    }
    if (i < Bb * Nn) {   // per-(b,point) frags for chamfer; (b*Nn+p) == i
        const long e = (long)i * 3;
        tFrag[i] = a_frag(targ[e], targ[e + 1], targ[e + 2]);
        pFrag[i] = a_frag(tmpl[e] + disp[e], tmpl[e + 1] + disp[e + 1],
                          tmpl[e + 2] + disp[e + 2]);
    }
}

// --- fat kernel (512 thr): knn blocks [0,256) + 2-unit chamfer blocks [256,768) ---
__global__ __launch_bounds__(512, 3) void fat_kernel(
    const float* __restrict__ disp, const float* __restrict__ tmpl,
    const float* __restrict__ targ, unsigned* __restrict__ outMin,
    float* __restrict__ acc, const half8* __restrict__ tmplFrag,
    const half8* __restrict__ pFrag, const half8* __restrict__ tFrag) {
    __shared__ KnnSmem sm;
    const int tid = threadIdx.x;
    const int lane = tid & 63, w = tid >> 6;      // w = 0..7
    const int l31 = lane & 31, hi = (lane >> 5) & 1;
    const f32x16 zc = {0.f, 0.f, 0.f, 0.f, 0.f, 0.f, 0.f, 0.f,
                       0.f, 0.f, 0.f, 0.f, 0.f, 0.f, 0.f, 0.f};

    if (blockIdx.x >= KNN_BLOCKS) {
        // ===== chamfer via MFMA: two independent 256-thread units per block =====
        const int cbu = ((int)blockIdx.x - KNN_BLOCKS) * 2 + (w >> 2);  // 0..1023
        const int wq = w & 3;
        const int qbase = (cbu & 15) * 512;
        const int eighth = (cbu >> 4) & 7;
        const int bd = cbu >> 7;                       // 0..7
        const int dir = bd & 1, b = bd >> 1;
        const int kg = lane >> 5;

        float qq[4];
        half8 Bf[4];
        #pragma unroll
        for (int j = 0; j < 4; ++j) {
            const int q = qbase + wq * 128 + j * 32 + l31;
            const long e = ((long)b * Nn + q) * 3;
            float x, y, z;
            if (dir == 0) {   // queries = pred
                x = tmpl[e] + disp[e]; y = tmpl[e+1] + disp[e+1]; z = tmpl[e+2] + disp[e+2];
            } else {          // queries = targ
                x = targ[e]; y = targ[e+1]; z = targ[e+2];
            }
            _Float16 hx = (_Float16)x, hy = (_Float16)y, hz = (_Float16)z;
            const float xr = (float)hx, yr = (float)hy, zr = (float)hz;
            qq[j] = xr * xr + yr * yr + zr * zr;
            Bf[j] = (kg == 0) ? b_frag(x, y, z) : zero8();
        }

        // points = the other set's frags, this (b, eighth)
        const half8* pf = ((dir == 0) ? tFrag : pFrag) + (long)b * Nn + eighth * 1024;

        float run[4] = {1e38f, 1e38f, 1e38f, 1e38f};

        #pragma unroll 1
        for (int g = 0; g < 8; ++g) {        // 8 groups x 4-deep batched loads
            half8 a[4];
            #pragma unroll
            for (int k = 0; k < 4; ++k)
                a[k] = pf[(g * 4 + k) * 32 + l31];
            #pragma unroll
            for (int k = 0; k < 4; ++k) {
                #pragma unroll
                for (int j = 0; j < 4; ++j) {
                    f32x16 c = __builtin_amdgcn_mfma_f32_32x32x16_f16(a[k], Bf[j], zc, 0, 0, 0);
                    #pragma unroll
                    for (int r = 0; r < 16; r += 2)
                        run[j] = fminf(run[j], fminf(c[r], c[r + 1]));  // -> v_min3_f32
                }
            }
        }

        #pragma unroll
        for (int j = 0; j < 4; ++j)
            run[j] = fminf(run[j], __shfl_xor(run[j], 32, 64));
        if (hi == 0) {
            const long base = ((long)dir * Bb + b) * Nn;
            #pragma unroll
            for (int j = 0; j < 4; ++j) {
                const int q = qbase + wq * 128 + j * 32 + l31;
                const float d2 = fmaxf(fmaf(2.0f, run[j], qq[j]), 0.0f);
                atomicMin(&outMin[base + q], __float_as_uint(d2));
            }
        }
    } else {
        // ====== knn via MFMA: 32 queries/block; 8 waves x 32 tiles each ======
        const int kb = blockIdx.x;                     // 0..255
        const int q = kb * 32 + l31;
        const float INFf = __uint_as_float(0x7f800000u);

        half8 Bf;
        {
            const float x = tmpl[q * 3 + 0], y = tmpl[q * 3 + 1], z = tmpl[q * 3 + 2];
            Bf = (hi == 0) ? b_frag(x, y, z) : zero8();
        }

        if (tid < 32) sm.cnt[tid] = 0;

        float cmn[16];
        #pragma unroll
        for (int r = 0; r < 16; ++r) cmn[r] = INFf;

        // ---- phase A: 4 batches of {8 loads in flight -> 8 MFMA+fmin} ----
        #pragma unroll 1
        for (int g = 0; g < 4; ++g) {
            half8 a[8];
            #pragma unroll
            for (int j = 0; j < 8; ++j)
                a[j] = tmplFrag[(w * 32 + g * 8 + j) * 32 + l31];
            #pragma unroll
            for (int j = 0; j < 8; ++j) {
                f32x16 c = __builtin_amdgcn_mfma_f32_32x32x16_f16(a[j], Bf, zc, 0, 0, 0);
                #pragma unroll
                for (int r = 0; r < 16; ++r) cmn[r] = fminf(cmn[r], c[r]);
            }
        }

        // ---- per-wave T_w = 7th-smallest of its 32 chunk-mins ----
        float Tw = INFf;
        #pragma unroll
        for (int t = 0; t < 7; ++t) {
            float h = cmn[0];
            #pragma unroll
            for (int r = 1; r < 16; ++r) h = fminf(h, cmn[r]);
            h = fminf(h, __shfl_xor(h, 32, 64));
            Tw = h;
            #pragma unroll
            for (int r = 0; r < 16; ++r) cmn[r] = (cmn[r] == h) ? INFf : cmn[r];
        }
        if (hi == 0) sm.Tbuf[w * 32 + l31] = Tw;
        __syncthreads();
        // T = min over the 8 waves: valid bound (argmin wave's eighth has >=7 pts <= T)
        float T = sm.Tbuf[l31];
        #pragma unroll
        for (int ww = 1; ww < 8; ++ww) T = fminf(T, sm.Tbuf[ww * 32 + l31]);

        // ---- phase B: rescan own tiles (batched); collect candidates (c <= T) ----
        #pragma unroll 1
        for (int g = 0; g < 4; ++g) {
            half8 a[8];
            #pragma unroll
            for (int j = 0; j < 8; ++j)
                a[j] = tmplFrag[(w * 32 + g * 8 + j) * 32 + l31];
            #pragma unroll
            for (int j = 0; j < 8; ++j) {
                const int tt = w * 32 + g * 8 + j;
                f32x16 c = __builtin_amdgcn_mfma_f32_32x32x16_f16(a[j], Bf, zc, 0, 0, 0);
                #pragma unroll
                for (int r = 0; r < 16; ++r) {
                    if (c[r] <= T) {
                        const int row = (r & 3) + 8 * (r >> 2) + 4 * hi;   // verified C/D map
                        const int p = tt * 32 + row;
                        const unsigned key = (ordkey(c[r]) & 0xFFFFE000u) | (unsigned)p;
                        const int pos = atomicAdd(&sm.cnt[l31], 1);
                        if (pos < KCAP) sm.cand[l31][pos] = key;
                    }
                }
            }
        }
        __syncthreads();

        // ---- exact top-7 (f16 metric, index tie-break) + smooth; 1 thread/query ----
        if (tid < 32) {
            const int qs = kb * 32 + tid;
            const int m = min(sm.cnt[tid], KCAP);
            unsigned l0 = ~0u, l1 = ~0u, l2 = ~0u, l3 = ~0u,
                     l4 = ~0u, l5 = ~0u, l6 = ~0u;
            for (int t = 0; t < m; ++t) {
                const unsigned key = sm.cand[tid][t];
                if (key < l6) {
                    l6 = key;
                    if (l6 < l5) { auto tt = l5; l5 = l6; l6 = tt; }
                    if (l5 < l4) { auto tt = l4; l4 = l5; l5 = tt; }
                    if (l4 < l3) { auto tt = l3; l3 = l4; l4 = tt; }
                    if (l3 < l2) { auto tt = l2; l2 = l3; l3 = tt; }
                    if (l2 < l1) { auto tt = l1; l1 = l2; l2 = tt; }
                    if (l1 < l0) { auto tt = l0; l0 = l1; l1 = tt; }
                }
            }
            // l0 = self (global-min); neighbors l1..l6
            int nb[6] = { (int)(l1 & 0x1FFFu), (int)(l2 & 0x1FFFu), (int)(l3 & 0x1FFFu),
                          (int)(l4 & 0x1FFFu), (int)(l5 & 0x1FFFu), (int)(l6 & 0x1FFFu) };
            float s = 0.0f;
            #pragma unroll
            for (int k = 0; k < 6; ++k) {
                const int j = nb[k];
                #pragma unroll
                for (int bb = 0; bb < Bb; ++bb) {
                    const float* dn = disp + ((long)bb * Nn + qs) * 3;
                    const float* dj = disp + ((long)bb * Nn + j) * 3;
                    const float ddx = dj[0] - dn[0];
                    const float ddy = dj[1] - dn[1];
                    const float ddz = dj[2] - dn[2];
                    s += ddx * ddx + ddy * ddy + ddz * ddz;
                }
            }
            sm.part[tid] = s;
        }
        __syncthreads();
        if (tid == 0) {
            float tot = 0.0f;
            #pragma unroll
            for (int i = 0; i < 32; ++i) tot += sm.part[i];
            atomicAdd(&acc[3], tot);
        }
    }
}

// ---- fused tail: reductions + last-block finalize ----
__global__ __launch_bounds__(256) void tail_reduce_kernel(
    const float* __restrict__ minArr, const float* __restrict__ pm,
    const float* __restrict__ tm, const float* __restrict__ dp,
    float* __restrict__ acc, float* __restrict__ out) {
    const int tid = threadIdx.x;
    const int stride = gridDim.x * blockDim.x;
    float sc = 0.0f, sm = 0.0f, sd = 0.0f;
    for (int i = blockIdx.x * blockDim.x + tid; i < 2 * Bb * Nn; i += stride) {
        sc += sqrtf(fmaxf(minArr[i], 1e-12f));
    }
    for (int i = blockIdx.x * blockDim.x + tid; i < Bb * Nn * 4; i += stride) {
        float d = pm[i] - tm[i];
        sm += d * d;
    }
    for (int i = blockIdx.x * blockDim.x + tid; i < Bb * Nn * 3; i += stride) {
        float v = dp[i];
        sd += v * v;
    }
    __shared__ float r0[256], r1[256], r2[256];
    r0[tid] = sc; r1[tid] = sm; r2[tid] = sd;
    __syncthreads();
    for (int w = 128; w > 0; w >>= 1) {
        if (tid < w) { r0[tid] += r0[tid + w]; r1[tid] += r1[tid + w]; r2[tid] += r2[tid + w]; }
        __syncthreads();
    }
    if (tid == 0) {
        atomicAdd(&acc[0], r0[0]);
        atomicAdd(&acc[1], r1[0]);
        atomicAdd(&acc[2], r2[0]);
        __threadfence();
        const unsigned done = atomicAdd((unsigned*)&acc[7], 1u);
        if (done == (unsigned)(gridDim.x - 1)) {
            const float c0 = atomicAdd(&acc[0], 0.0f);
            const float c1 = atomicAdd(&acc[1], 0.0f);
            const float c2 = atomicAdd(&acc[2], 0.0f);
            const float c3 = atomicAdd(&acc[3], 0.0f);
            const float cd  = c0 / (2.0f * Bb * Nn);
            const float mat = c1 / (float)(Bb * Nn * 4);
            const float dr  = c2 / (float)(Bb * Nn * 3);
            const float smo = c3 / (float)(Bb * Nn * KNB * 3);
            out[0] = 1.0f * cd + 0.1f * mat + 0.01f * dr + 0.005f * smo;
        }
    }
}

}  // namespace

extern "C" void kernel_launch(void* const* d_in, const int* in_sizes, int n_in,
                              void* d_out, int out_size, void* d_ws, size_t ws_size,
                              hipStream_t stream) {
    const float* pred_disp  = (const float*)d_in[0];
    const float* pred_mat   = (const float*)d_in[1];
    const float* target_pos = (const float*)d_in[2];
    const float* target_mat = (const float*)d_in[3];
    const float* tmpl       = (const float*)d_in[4];

    char* ws = (char*)d_ws;
    unsigned* minArr = (unsigned*)ws;                       // 256 KB
    float* acc = (float*)(ws + 262144);                     // 64 B
    half8* tmplFrag = (half8*)(ws + 262144 + 64);           // 128 KB
    half8* pFrag = (half8*)(ws + 262144 + 64 + 131072);     // 512 KB
    half8* tFrag = (half8*)(ws + 262144 + 64 + 131072 + 524288);  // 512 KB

    init_ws_kernel<<<(Bb * Nn) / 256 + 32, 256, 0, stream>>>(
        minArr, acc, tmplFrag, pFrag, tFrag, tmpl, pred_disp, target_pos);

    fat_kernel<<<KNN_BLOCKS + CH_BLOCKS, 512, 0, stream>>>(
        pred_disp, tmpl, target_pos, minArr, acc, tmplFrag, pFrag, tFrag);

    tail_reduce_kernel<<<TAIL_BLOCKS, 256, 0, stream>>>(
        (const float*)minArr, pred_mat, target_mat, pred_disp, acc, (float*)d_out);
}